// Round 17
// baseline (178.220 us; speedup 1.0000x reference)
//
#include <hip/hip_runtime.h>

#define N_NODES 100000
#define IN_C    128
#define HID_C   64
#define OUT_C   40
#define N_EDGES 1600000

// bucketed build: 256 dst-nodes per bucket, fixed-capacity slabs
#define BSH        8
#define NBUCK      ((N_NODES + 255) >> BSH)              // 391
#define CAP        5120                                  // per-bucket edge slab
#define PART_CHUNK 4096
#define NPB        ((N_EDGES + PART_CHUNK - 1) / PART_CHUNK)  // 391
#define EPT        (PART_CHUNK / 256)

typedef _Float16 half_t;
typedef _Float16 half8   __attribute__((ext_vector_type(8)));
typedef _Float16 half2_t __attribute__((ext_vector_type(2)));
typedef float    f32x4   __attribute__((ext_vector_type(4)));
typedef unsigned long long ull;

// dequant-accumulate 16 int8 channels (uint4) with row scale into a[0..15]
static __device__ __forceinline__ void acc16(float* a, uint4 v, float sc) {
    char4 c0 = __builtin_bit_cast(char4, v.x);
    char4 c1 = __builtin_bit_cast(char4, v.y);
    char4 c2 = __builtin_bit_cast(char4, v.z);
    char4 c3 = __builtin_bit_cast(char4, v.w);
    a[0]  += sc * (float)c0.x; a[1]  += sc * (float)c0.y;
    a[2]  += sc * (float)c0.z; a[3]  += sc * (float)c0.w;
    a[4]  += sc * (float)c1.x; a[5]  += sc * (float)c1.y;
    a[6]  += sc * (float)c1.z; a[7]  += sc * (float)c1.w;
    a[8]  += sc * (float)c2.x; a[9]  += sc * (float)c2.y;
    a[10] += sc * (float)c2.z; a[11] += sc * (float)c2.w;
    a[12] += sc * (float)c3.x; a[13] += sc * (float)c3.y;
    a[14] += sc * (float)c3.z; a[15] += sc * (float)c3.w;
}

// ---------------------------------------------------------------------------
// init: seed bucket cursors + W1 -> W1T fp16 + W2 -> W2T fp16
// ---------------------------------------------------------------------------
__global__ void k_init(const float* __restrict__ W1, const float* __restrict__ W2,
                       half_t* __restrict__ W1T, half_t* __restrict__ W2T,
                       int* __restrict__ gcur) {
    int t = threadIdx.x;  // 512
    if (t < NBUCK) gcur[t] = t * CAP;
    for (int i = t; i < IN_C * HID_C; i += 512) {
        int k = i >> 6, n = i & 63;
        W1T[n * IN_C + k] = (half_t)W1[i];
    }
    for (int i = t; i < 48 * HID_C; i += 512) {
        int n = i >> 6, k = i & 63;
        W2T[n * HID_C + k] = (n < OUT_C) ? (half_t)W2[k * OUT_C + n] : (half_t)0.0f;
    }
}

// ---------------------------------------------------------------------------
// partition edges into bucket slabs; 5B encoding (srcs 4B + d8 1B)
// ---------------------------------------------------------------------------
__global__ void k_part(const int* __restrict__ src, const int* __restrict__ dst,
                       int* __restrict__ gcur, int* __restrict__ srcs,
                       unsigned char* __restrict__ d8) {
    __shared__ int lh[NBUCK];
    int tid = threadIdx.x;
    for (int i = tid; i < NBUCK; i += 256) lh[i] = 0;
    __syncthreads();
    int base = blockIdx.x * PART_CHUNK;
    int sv[EPT], dv[EPT], rv[EPT];
#pragma unroll
    for (int j = 0; j < EPT; ++j) {
        int e = base + j * 256 + tid;
        if (e < N_EDGES) {
            sv[j] = src[e];
            dv[j] = dst[e];
            rv[j] = atomicAdd(&lh[dv[j] >> BSH], 1);
        } else {
            dv[j] = -1;
        }
    }
    __syncthreads();
    for (int i = tid; i < NBUCK; i += 256) {
        int c = lh[i];
        if (c) lh[i] = atomicAdd(&gcur[i], c);
    }
    __syncthreads();
#pragma unroll
    for (int j = 0; j < EPT; ++j) {
        if (dv[j] >= 0) {
            int pos = lh[dv[j] >> BSH] + rv[j];
            srcs[pos] = sv[j];
            d8[pos]   = (unsigned char)(dv[j] & 255);
        }
    }
}

// ---------------------------------------------------------------------------
// fused per-bucket build: count (d8) -> LDS scan -> cursor/cnt/dinv -> fill
// ---------------------------------------------------------------------------
__global__ void k_bbuild(const int* __restrict__ srcs, const unsigned char* __restrict__ d8,
                         const int* __restrict__ gcur, int* __restrict__ cursor,
                         int* __restrict__ cnt, float* __restrict__ dinv,
                         int* __restrict__ esrc) {
    __shared__ int lc[256];
    __shared__ int ls[256];
    __shared__ int lcur[256];
    int b = blockIdx.x, tid = threadIdx.x;
    int nbase = b << BSH;
    int s0 = b * CAP, s1 = gcur[b];

    lc[tid] = 0;
    __syncthreads();
    for (int e = s0 + tid; e < s1; e += 256)
        atomicAdd(&lc[d8[e]], 1);
    __syncthreads();

    int v = lc[tid];
    ls[tid] = v;
    __syncthreads();
    for (int off = 1; off < 256; off <<= 1) {
        int t = (tid >= off) ? ls[tid - off] : 0;
        __syncthreads();
        ls[tid] += t;
        __syncthreads();
    }
    int excl = ls[tid] - v;
    int node = nbase + tid;
    int rowstart = s0 + excl;
    lcur[tid] = rowstart;
    if (node < N_NODES) {
        cursor[node] = rowstart;
        cnt[node]    = v;
        dinv[node]   = rsqrtf(1.0f + (float)v);
    }
    __syncthreads();

    for (int e = s0 + tid; e < s1; e += 256) {
        int d = d8[e];
        int s = srcs[e];
        int pos = atomicAdd(&lcur[d], 1);
        esrc[pos] = s;
    }
}

// ---------------------------------------------------------------------------
// MFMA GEMM1 + int8 quantization (64B rows)
// ---------------------------------------------------------------------------
__global__ void k_gemm1_mfma(const float* __restrict__ x, const half_t* __restrict__ W1T,
                             const float* __restrict__ dinv, signed char* __restrict__ g1q,
                             float* __restrict__ scales) {
    __shared__ __align__(16) signed char lq[16 * HID_C];
    int lane = threadIdx.x & 63;
    int l16  = lane & 15;
    int lg   = lane >> 4;

    half8 bf[4][4];
#pragma unroll
    for (int ct = 0; ct < 4; ++ct)
#pragma unroll
        for (int kc = 0; kc < 4; ++kc)
            bf[ct][kc] = *(const half8*)(W1T + (ct * 16 + l16) * IN_C + kc * 32 + lg * 8);

#pragma unroll
    for (int s = 0; s < 2; ++s) {
        int r0 = (blockIdx.x * 2 + s) * 16;
        f32x4 acc0 = {0.f, 0.f, 0.f, 0.f};
        f32x4 acc1 = {0.f, 0.f, 0.f, 0.f};
        f32x4 acc2 = {0.f, 0.f, 0.f, 0.f};
        f32x4 acc3 = {0.f, 0.f, 0.f, 0.f};
#pragma unroll
        for (int kc = 0; kc < 4; ++kc) {
            const float* ap = x + (size_t)(r0 + l16) * IN_C + kc * 32 + lg * 8;
            float4 a0 = *(const float4*)ap;
            float4 a1 = *(const float4*)(ap + 4);
            half8 af;
            af[0] = (_Float16)a0.x; af[1] = (_Float16)a0.y;
            af[2] = (_Float16)a0.z; af[3] = (_Float16)a0.w;
            af[4] = (_Float16)a1.x; af[5] = (_Float16)a1.y;
            af[6] = (_Float16)a1.z; af[7] = (_Float16)a1.w;
            acc0 = __builtin_amdgcn_mfma_f32_16x16x32_f16(af, bf[0][kc], acc0, 0, 0, 0);
            acc1 = __builtin_amdgcn_mfma_f32_16x16x32_f16(af, bf[1][kc], acc1, 0, 0, 0);
            acc2 = __builtin_amdgcn_mfma_f32_16x16x32_f16(af, bf[2][kc], acc2, 0, 0, 0);
            acc3 = __builtin_amdgcn_mfma_f32_16x16x32_f16(af, bf[3][kc], acc3, 0, 0, 0);
        }
#pragma unroll
        for (int j = 0; j < 4; ++j) {
            int   r  = r0 + lg * 4 + j;
            float dv = dinv[r];
            float v0 = acc0[j] * dv;
            float v1 = acc1[j] * dv;
            float v2 = acc2[j] * dv;
            float v3 = acc3[j] * dv;
            float m = fmaxf(fmaxf(fabsf(v0), fabsf(v1)), fmaxf(fabsf(v2), fabsf(v3)));
            m = fmaxf(m, __shfl_xor(m, 1));
            m = fmaxf(m, __shfl_xor(m, 2));
            m = fmaxf(m, __shfl_xor(m, 4));
            m = fmaxf(m, __shfl_xor(m, 8));
            float inv = (m > 0.0f) ? 127.0f / m : 0.0f;
            if (l16 == 0) scales[r] = m * (1.0f / 127.0f);
            int q0 = min(127, max(-127, __float2int_rn(v0 * inv)));
            int q1 = min(127, max(-127, __float2int_rn(v1 * inv)));
            int q2 = min(127, max(-127, __float2int_rn(v2 * inv)));
            int q3 = min(127, max(-127, __float2int_rn(v3 * inv)));
            int rl = lg * 4 + j;
            lq[rl * HID_C +  0 + l16] = (signed char)q0;
            lq[rl * HID_C + 16 + l16] = (signed char)q1;
            lq[rl * HID_C + 32 + l16] = (signed char)q2;
            lq[rl * HID_C + 48 + l16] = (signed char)q3;
        }
        uint4 wv = *(const uint4*)(lq + lane * 16);
        *(uint4*)(g1q + (size_t)r0 * HID_C + lane * 16) = wv;
    }
}

// ---------------------------------------------------------------------------
// pull layer1: 2 nodes/wave, 8 slots x 4 lanes x uint4; unroll-4 main loop
// (4 independent esrc->gather chains in flight per lane).
// ---------------------------------------------------------------------------
__global__ void k_pull1(const int* __restrict__ cursor, const int* __restrict__ cnt,
                        const int* __restrict__ esrc, const float* __restrict__ dinv,
                        const uint4* __restrict__ g1v, const float* __restrict__ scales,
                        const float* __restrict__ b1, half_t* __restrict__ h1) {
    int w    = threadIdx.x >> 6;
    int lane = threadIdx.x & 63;
    int hl   = lane & 31;
    int hh   = lane >> 5;            // half 0/1 -> node
    int slot = hl >> 2;              // 0..7
    int c16  = hl & 3;               // 16-channel chunk (16B)
    int n    = blockIdx.x * 8 + w * 2 + hh;

    float dn  = dinv[n];
    int start = cursor[n];
    int mycnt = cnt[n];

    float a[16];
#pragma unroll
    for (int j = 0; j < 16; ++j) a[j] = 0.f;
    if (slot == 0)
        acc16(a, g1v[(size_t)n * 4 + c16], scales[n]);  // self row

    int maxcnt = max(mycnt, __shfl_xor(mycnt, 32));     // wave-uniform

    int e = 0;
    for (; e + 32 <= maxcnt; e += 32) {
        bool ok0 = (e + slot) < mycnt;
        bool ok1 = (e + 8 + slot) < mycnt;
        bool ok2 = (e + 16 + slot) < mycnt;
        bool ok3 = (e + 24 + slot) < mycnt;
        int i0 = esrc[ok0 ? (start + e + slot) : start];
        int i1 = esrc[ok1 ? (start + e + 8 + slot) : start];
        int i2 = esrc[ok2 ? (start + e + 16 + slot) : start];
        int i3 = esrc[ok3 ? (start + e + 24 + slot) : start];
        i0 = ok0 ? i0 : 0;
        i1 = ok1 ? i1 : 0;
        i2 = ok2 ? i2 : 0;
        i3 = ok3 ? i3 : 0;
        uint4 v0 = g1v[(size_t)i0 * 4 + c16];
        float s0 = ok0 ? scales[i0] : 0.f;
        uint4 v1 = g1v[(size_t)i1 * 4 + c16];
        float s1 = ok1 ? scales[i1] : 0.f;
        uint4 v2 = g1v[(size_t)i2 * 4 + c16];
        float s2 = ok2 ? scales[i2] : 0.f;
        uint4 v3 = g1v[(size_t)i3 * 4 + c16];
        float s3 = ok3 ? scales[i3] : 0.f;
        acc16(a, v0, s0);
        acc16(a, v1, s1);
        acc16(a, v2, s2);
        acc16(a, v3, s3);
    }
    for (; e + 16 <= maxcnt; e += 16) {
        bool ok0 = (e + slot) < mycnt;
        bool ok1 = (e + 8 + slot) < mycnt;
        int i0 = esrc[ok0 ? (start + e + slot) : start];
        int i1 = esrc[ok1 ? (start + e + 8 + slot) : start];
        i0 = ok0 ? i0 : 0;
        i1 = ok1 ? i1 : 0;
        uint4 v0 = g1v[(size_t)i0 * 4 + c16];
        float s0 = ok0 ? scales[i0] : 0.f;
        uint4 v1 = g1v[(size_t)i1 * 4 + c16];
        float s1 = ok1 ? scales[i1] : 0.f;
        acc16(a, v0, s0);
        acc16(a, v1, s1);
    }
    for (; e < maxcnt; e += 8) {
        bool ok = (e + slot) < mycnt;
        int idx = esrc[ok ? (start + e + slot) : start];
        idx = ok ? idx : 0;
        uint4 v = g1v[(size_t)idx * 4 + c16];
        float s = ok ? scales[idx] : 0.f;
        acc16(a, v, s);
    }

#pragma unroll
    for (int j = 0; j < 16; ++j) {
        a[j] += __shfl_xor(a[j], 4);
        a[j] += __shfl_xor(a[j], 8);
        a[j] += __shfl_xor(a[j], 16);
    }

    if (slot == 0) {
        const float4* bp = (const float4*)(b1 + c16 * 16);
        uint4 u0, u1;
        unsigned us[8];
#pragma unroll
        for (int q = 0; q < 4; ++q) {
            float4 bb = bp[q];
            float r0 = fmaxf(dn * a[q * 4 + 0] + bb.x, 0.f);
            float r1 = fmaxf(dn * a[q * 4 + 1] + bb.y, 0.f);
            float r2 = fmaxf(dn * a[q * 4 + 2] + bb.z, 0.f);
            float r3 = fmaxf(dn * a[q * 4 + 3] + bb.w, 0.f);
            half2_t p0; p0.x = (_Float16)r0; p0.y = (_Float16)r1;
            half2_t p1; p1.x = (_Float16)r2; p1.y = (_Float16)r3;
            us[q * 2 + 0] = __builtin_bit_cast(unsigned, p0);
            us[q * 2 + 1] = __builtin_bit_cast(unsigned, p1);
        }
        u0.x = us[0]; u0.y = us[1]; u0.z = us[2]; u0.w = us[3];
        u1.x = us[4]; u1.y = us[5]; u1.z = us[6]; u1.w = us[7];
        half_t* hp = h1 + (size_t)n * HID_C + c16 * 16;
        *(uint4*)hp = u0;
        *(uint4*)(hp + 8) = u1;
    }
}

// ---------------------------------------------------------------------------
// MFMA GEMM2: g2 = dinv * (h1 @ W2), int8 row-quantized, 64B PADDED rows
// (40 data + 24 zero) + scales2. LDS block zero-initialized.
// ---------------------------------------------------------------------------
__global__ void k_gemm2_mfma(const half_t* __restrict__ h1, const half_t* __restrict__ W2T,
                             const float* __restrict__ dinv, signed char* __restrict__ g2q,
                             float* __restrict__ scales2) {
    __shared__ __align__(16) signed char lq[16 * 64];
    int lane = threadIdx.x & 63;
    int l16  = lane & 15;
    int lg   = lane >> 4;

    half8 bf[3][2];
#pragma unroll
    for (int ct = 0; ct < 3; ++ct)
#pragma unroll
        for (int kc = 0; kc < 2; ++kc)
            bf[ct][kc] = *(const half8*)(W2T + (ct * 16 + l16) * HID_C + kc * 32 + lg * 8);

#pragma unroll
    for (int s = 0; s < 2; ++s) {
        int r0 = (blockIdx.x * 2 + s) * 16;
        // zero the staging block (covers the 24B/row padding)
        ((uint4*)lq)[lane] = uint4{0u, 0u, 0u, 0u};
        f32x4 acc0 = {0.f, 0.f, 0.f, 0.f};
        f32x4 acc1 = {0.f, 0.f, 0.f, 0.f};
        f32x4 acc2 = {0.f, 0.f, 0.f, 0.f};
#pragma unroll
        for (int kc = 0; kc < 2; ++kc) {
            half8 af = *(const half8*)(h1 + (size_t)(r0 + l16) * HID_C + kc * 32 + lg * 8);
            acc0 = __builtin_amdgcn_mfma_f32_16x16x32_f16(af, bf[0][kc], acc0, 0, 0, 0);
            acc1 = __builtin_amdgcn_mfma_f32_16x16x32_f16(af, bf[1][kc], acc1, 0, 0, 0);
            acc2 = __builtin_amdgcn_mfma_f32_16x16x32_f16(af, bf[2][kc], acc2, 0, 0, 0);
        }
#pragma unroll
        for (int j = 0; j < 4; ++j) {
            int   r  = r0 + lg * 4 + j;
            float dv = dinv[r];
            float v0 = acc0[j] * dv;
            float v1 = acc1[j] * dv;
            float v2 = (l16 < 8) ? acc2[j] * dv : 0.0f;
            float m = fmaxf(fmaxf(fabsf(v0), fabsf(v1)), fabsf(v2));
            m = fmaxf(m, __shfl_xor(m, 1));
            m = fmaxf(m, __shfl_xor(m, 2));
            m = fmaxf(m, __shfl_xor(m, 4));
            m = fmaxf(m, __shfl_xor(m, 8));
            float inv = (m > 0.0f) ? 127.0f / m : 0.0f;
            if (l16 == 0) scales2[r] = m * (1.0f / 127.0f);
            int q0 = min(127, max(-127, __float2int_rn(v0 * inv)));
            int q1 = min(127, max(-127, __float2int_rn(v1 * inv)));
            int q2 = min(127, max(-127, __float2int_rn(v2 * inv)));
            int rl = lg * 4 + j;
            lq[rl * 64 +  0 + l16] = (signed char)q0;
            lq[rl * 64 + 16 + l16] = (signed char)q1;
            if (l16 < 8) lq[rl * 64 + 32 + l16] = (signed char)q2;
        }
        // 16 rows x 64B = 1024B = 64 lanes x 16B
        *(uint4*)(g2q + (size_t)r0 * 64 + lane * 16) = ((const uint4*)lq)[lane];
    }
}

// ---------------------------------------------------------------------------
// pull layer2 -> out: 2 nodes/wave, 8 slots x 4 lanes x uint4, 64B padded
// rows (padding = 0). Unroll-4 main loop. Butterfly; slot0 writes 40 fp32.
// ---------------------------------------------------------------------------
__global__ void k_pull2(const int* __restrict__ cursor, const int* __restrict__ cnt,
                        const int* __restrict__ esrc, const float* __restrict__ dinv,
                        const uint4* __restrict__ g2v, const float* __restrict__ scales2,
                        const float* __restrict__ b2, float* __restrict__ out) {
    int w    = threadIdx.x >> 6;
    int lane = threadIdx.x & 63;
    int hl   = lane & 31;
    int hh   = lane >> 5;            // half 0/1 -> node
    int slot = hl >> 2;              // 0..7
    int c16  = hl & 3;               // 16-channel chunk
    int n    = blockIdx.x * 8 + w * 2 + hh;

    float dn  = dinv[n];
    int start = cursor[n];
    int mycnt = cnt[n];

    float a[16];
#pragma unroll
    for (int j = 0; j < 16; ++j) a[j] = 0.f;
    if (slot == 0)
        acc16(a, g2v[(size_t)n * 4 + c16], scales2[n]);  // self row

    int maxcnt = max(mycnt, __shfl_xor(mycnt, 32));      // wave-uniform

    int e = 0;
    for (; e + 32 <= maxcnt; e += 32) {
        bool ok0 = (e + slot) < mycnt;
        bool ok1 = (e + 8 + slot) < mycnt;
        bool ok2 = (e + 16 + slot) < mycnt;
        bool ok3 = (e + 24 + slot) < mycnt;
        int i0 = esrc[ok0 ? (start + e + slot) : start];
        int i1 = esrc[ok1 ? (start + e + 8 + slot) : start];
        int i2 = esrc[ok2 ? (start + e + 16 + slot) : start];
        int i3 = esrc[ok3 ? (start + e + 24 + slot) : start];
        i0 = ok0 ? i0 : 0;
        i1 = ok1 ? i1 : 0;
        i2 = ok2 ? i2 : 0;
        i3 = ok3 ? i3 : 0;
        uint4 v0 = g2v[(size_t)i0 * 4 + c16];
        float s0 = ok0 ? scales2[i0] : 0.f;
        uint4 v1 = g2v[(size_t)i1 * 4 + c16];
        float s1 = ok1 ? scales2[i1] : 0.f;
        uint4 v2 = g2v[(size_t)i2 * 4 + c16];
        float s2 = ok2 ? scales2[i2] : 0.f;
        uint4 v3 = g2v[(size_t)i3 * 4 + c16];
        float s3 = ok3 ? scales2[i3] : 0.f;
        acc16(a, v0, s0);
        acc16(a, v1, s1);
        acc16(a, v2, s2);
        acc16(a, v3, s3);
    }
    for (; e + 16 <= maxcnt; e += 16) {
        bool ok0 = (e + slot) < mycnt;
        bool ok1 = (e + 8 + slot) < mycnt;
        int i0 = esrc[ok0 ? (start + e + slot) : start];
        int i1 = esrc[ok1 ? (start + e + 8 + slot) : start];
        i0 = ok0 ? i0 : 0;
        i1 = ok1 ? i1 : 0;
        uint4 v0 = g2v[(size_t)i0 * 4 + c16];
        float s0 = ok0 ? scales2[i0] : 0.f;
        uint4 v1 = g2v[(size_t)i1 * 4 + c16];
        float s1 = ok1 ? scales2[i1] : 0.f;
        acc16(a, v0, s0);
        acc16(a, v1, s1);
    }
    for (; e < maxcnt; e += 8) {
        bool ok = (e + slot) < mycnt;
        int idx = esrc[ok ? (start + e + slot) : start];
        idx = ok ? idx : 0;
        uint4 v = g2v[(size_t)idx * 4 + c16];
        float s = ok ? scales2[idx] : 0.f;
        acc16(a, v, s);
    }

#pragma unroll
    for (int j = 0; j < 16; ++j) {
        a[j] += __shfl_xor(a[j], 4);
        a[j] += __shfl_xor(a[j], 8);
        a[j] += __shfl_xor(a[j], 16);
    }

    if (slot == 0 && c16 < 3) {
        int nvalid = (c16 < 2) ? 16 : 8;   // channels c16*16 .. +nvalid
        const float* bp = b2 + c16 * 16;
        float* op = out + (size_t)n * OUT_C + c16 * 16;
#pragma unroll
        for (int q = 0; q < 4; ++q) {
            if (q * 4 < nvalid) {
                float4 r;
                r.x = bp[q * 4 + 0] + dn * a[q * 4 + 0];
                r.y = bp[q * 4 + 1] + dn * a[q * 4 + 1];
                r.z = bp[q * 4 + 2] + dn * a[q * 4 + 2];
                r.w = bp[q * 4 + 3] + dn * a[q * 4 + 3];
                ((float4*)op)[q] = r;
            }
        }
    }
}

// ---------------------------------------------------------------------------
// launch
// ---------------------------------------------------------------------------
extern "C" void kernel_launch(void* const* d_in, const int* in_sizes, int n_in,
                              void* d_out, int out_size, void* d_ws, size_t ws_size,
                              hipStream_t stream) {
    const float* x   = (const float*)d_in[0];
    const int*   ei  = (const int*)d_in[1];
    const int*   src = ei;
    const int*   dst = ei + N_EDGES;
    const float* W1  = (const float*)d_in[2];
    const float* b1  = (const float*)d_in[3];
    const float* W2  = (const float*)d_in[4];
    const float* b2  = (const float*)d_in[5];
    float*       out = (float*)d_out;

    // workspace (~46.5 MB; proven ws >= 51.6 MB)
    const int SLAB = NBUCK * CAP;                     // 2,001,920
    int*    cnt    = (int*)d_ws;                      // N
    int*    cursor = cnt + N_NODES;                   // N
    int*    gcur   = cursor + N_NODES;                // 512 (padded)
    half_t* w1t    = (half_t*)(gcur + 512);           // 8192 halfs
    half_t* w2t    = w1t + IN_C * HID_C;              // 3072 halfs
    float*  dinv   = (float*)(w2t + 48 * HID_C);      // N
    float*  scales = dinv + N_NODES;                  // N
    float*  scales2= scales + N_NODES;                // N
    int*    srcs   = (int*)(scales2 + N_NODES);       // SLAB+8 ints (8MB)
    int*    esrc   = srcs + SLAB + 8;                 // SLAB+8 ints (8MB)
    unsigned char* d8 = (unsigned char*)(esrc + SLAB + 8);              // SLAB bytes (2MB)
    signed char* g1q = (signed char*)(((uintptr_t)(d8 + SLAB) + 127) & ~(uintptr_t)127); // N*64B
    half_t* h1 = (half_t*)(g1q + (size_t)N_NODES * 64);                 // N*64 halfs
    signed char* g2q = (signed char*)(h1 + (size_t)N_NODES * HID_C);    // N*64B (padded)

    // build (3 kernels)
    k_init<<<1, 512, 0, stream>>>(W1, W2, w1t, w2t, gcur);
    k_part<<<NPB, 256, 0, stream>>>(src, dst, gcur, srcs, d8);
    k_bbuild<<<NBUCK, 256, 0, stream>>>(srcs, d8, gcur, cursor, cnt, dinv, esrc);

    // layer 1 transform: g1q = int8(dinv * (x @ W1)), per-row scales
    k_gemm1_mfma<<<N_NODES / 32, 64, 0, stream>>>(x, w1t, dinv, g1q, scales);

    // pull layer 1 -> h1 (fp16 hidden, bias+relu applied); 2 nodes/wave
    k_pull1<<<N_NODES / 8, 256, 0, stream>>>(cursor, cnt, esrc, dinv,
                                             (const uint4*)g1q, scales, b1, h1);

    // GEMM2 (MFMA): g2q = int8(dinv * (h1 @ W2)), 64B padded rows + scales2
    k_gemm2_mfma<<<N_NODES / 32, 64, 0, stream>>>(h1, w2t, dinv, g2q, scales2);

    // pull layer 2 -> out; 2 nodes/wave
    k_pull2<<<N_NODES / 8, 256, 0, stream>>>(cursor, cnt, esrc, dinv,
                                             (const uint4*)g2q, scales2, b2, out);
}

// Round 18
// 158.810 us; speedup vs baseline: 1.1222x; 1.1222x over previous
//
#include <hip/hip_runtime.h>

#define N_NODES 100000
#define IN_C    128
#define HID_C   64
#define OUT_C   40
#define N_EDGES 1600000

// bucketed build: 256 dst-nodes per bucket, fixed-capacity slabs
#define BSH        8
#define NBUCK      ((N_NODES + 255) >> BSH)              // 391
#define CAP        5120                                  // per-bucket edge slab
#define PART_CHUNK 4096
#define NPB        ((N_EDGES + PART_CHUNK - 1) / PART_CHUNK)  // 391
#define EPT        (PART_CHUNK / 256)

typedef _Float16 half_t;
typedef _Float16 half8   __attribute__((ext_vector_type(8)));
typedef _Float16 half2_t __attribute__((ext_vector_type(2)));
typedef float    f32x4   __attribute__((ext_vector_type(4)));
typedef unsigned long long ull;

// dequant-accumulate 16 int8 channels (uint4) with row scale into a[0..15]
static __device__ __forceinline__ void acc16(float* a, uint4 v, float sc) {
    char4 c0 = __builtin_bit_cast(char4, v.x);
    char4 c1 = __builtin_bit_cast(char4, v.y);
    char4 c2 = __builtin_bit_cast(char4, v.z);
    char4 c3 = __builtin_bit_cast(char4, v.w);
    a[0]  += sc * (float)c0.x; a[1]  += sc * (float)c0.y;
    a[2]  += sc * (float)c0.z; a[3]  += sc * (float)c0.w;
    a[4]  += sc * (float)c1.x; a[5]  += sc * (float)c1.y;
    a[6]  += sc * (float)c1.z; a[7]  += sc * (float)c1.w;
    a[8]  += sc * (float)c2.x; a[9]  += sc * (float)c2.y;
    a[10] += sc * (float)c2.z; a[11] += sc * (float)c2.w;
    a[12] += sc * (float)c3.x; a[13] += sc * (float)c3.y;
    a[14] += sc * (float)c3.z; a[15] += sc * (float)c3.w;
}

// ---------------------------------------------------------------------------
// init: seed bucket cursors + W1 -> W1T fp16 + W2 -> W2T fp16
// ---------------------------------------------------------------------------
__global__ void k_init(const float* __restrict__ W1, const float* __restrict__ W2,
                       half_t* __restrict__ W1T, half_t* __restrict__ W2T,
                       int* __restrict__ gcur) {
    int t = threadIdx.x;  // 512
    if (t < NBUCK) gcur[t] = t * CAP;
    for (int i = t; i < IN_C * HID_C; i += 512) {
        int k = i >> 6, n = i & 63;
        W1T[n * IN_C + k] = (half_t)W1[i];
    }
    for (int i = t; i < 48 * HID_C; i += 512) {
        int n = i >> 6, k = i & 63;
        W2T[n * HID_C + k] = (n < OUT_C) ? (half_t)W2[k * OUT_C + n] : (half_t)0.0f;
    }
}

// ---------------------------------------------------------------------------
// partition edges into bucket slabs; 5B encoding (srcs 4B + d8 1B)
// ---------------------------------------------------------------------------
__global__ void k_part(const int* __restrict__ src, const int* __restrict__ dst,
                       int* __restrict__ gcur, int* __restrict__ srcs,
                       unsigned char* __restrict__ d8) {
    __shared__ int lh[NBUCK];
    int tid = threadIdx.x;
    for (int i = tid; i < NBUCK; i += 256) lh[i] = 0;
    __syncthreads();
    int base = blockIdx.x * PART_CHUNK;
    int sv[EPT], dv[EPT], rv[EPT];
#pragma unroll
    for (int j = 0; j < EPT; ++j) {
        int e = base + j * 256 + tid;
        if (e < N_EDGES) {
            sv[j] = src[e];
            dv[j] = dst[e];
            rv[j] = atomicAdd(&lh[dv[j] >> BSH], 1);
        } else {
            dv[j] = -1;
        }
    }
    __syncthreads();
    for (int i = tid; i < NBUCK; i += 256) {
        int c = lh[i];
        if (c) lh[i] = atomicAdd(&gcur[i], c);
    }
    __syncthreads();
#pragma unroll
    for (int j = 0; j < EPT; ++j) {
        if (dv[j] >= 0) {
            int pos = lh[dv[j] >> BSH] + rv[j];
            srcs[pos] = sv[j];
            d8[pos]   = (unsigned char)(dv[j] & 255);
        }
    }
}

// ---------------------------------------------------------------------------
// fused per-bucket build: count (d8) -> LDS scan -> cursor/cnt/dinv -> fill
// ---------------------------------------------------------------------------
__global__ void k_bbuild(const int* __restrict__ srcs, const unsigned char* __restrict__ d8,
                         const int* __restrict__ gcur, int* __restrict__ cursor,
                         int* __restrict__ cnt, float* __restrict__ dinv,
                         int* __restrict__ esrc) {
    __shared__ int lc[256];
    __shared__ int ls[256];
    __shared__ int lcur[256];
    int b = blockIdx.x, tid = threadIdx.x;
    int nbase = b << BSH;
    int s0 = b * CAP, s1 = gcur[b];

    lc[tid] = 0;
    __syncthreads();
    for (int e = s0 + tid; e < s1; e += 256)
        atomicAdd(&lc[d8[e]], 1);
    __syncthreads();

    int v = lc[tid];
    ls[tid] = v;
    __syncthreads();
    for (int off = 1; off < 256; off <<= 1) {
        int t = (tid >= off) ? ls[tid - off] : 0;
        __syncthreads();
        ls[tid] += t;
        __syncthreads();
    }
    int excl = ls[tid] - v;
    int node = nbase + tid;
    int rowstart = s0 + excl;
    lcur[tid] = rowstart;
    if (node < N_NODES) {
        cursor[node] = rowstart;
        cnt[node]    = v;
        dinv[node]   = rsqrtf(1.0f + (float)v);
    }
    __syncthreads();

    for (int e = s0 + tid; e < s1; e += 256) {
        int d = d8[e];
        int s = srcs[e];
        int pos = atomicAdd(&lcur[d], 1);
        esrc[pos] = s;
    }
}

// ---------------------------------------------------------------------------
// MFMA GEMM1 + int8 quantization (64B rows)
// ---------------------------------------------------------------------------
__global__ void k_gemm1_mfma(const float* __restrict__ x, const half_t* __restrict__ W1T,
                             const float* __restrict__ dinv, signed char* __restrict__ g1q,
                             float* __restrict__ scales) {
    __shared__ __align__(16) signed char lq[16 * HID_C];
    int lane = threadIdx.x & 63;
    int l16  = lane & 15;
    int lg   = lane >> 4;

    half8 bf[4][4];
#pragma unroll
    for (int ct = 0; ct < 4; ++ct)
#pragma unroll
        for (int kc = 0; kc < 4; ++kc)
            bf[ct][kc] = *(const half8*)(W1T + (ct * 16 + l16) * IN_C + kc * 32 + lg * 8);

#pragma unroll
    for (int s = 0; s < 2; ++s) {
        int r0 = (blockIdx.x * 2 + s) * 16;
        f32x4 acc0 = {0.f, 0.f, 0.f, 0.f};
        f32x4 acc1 = {0.f, 0.f, 0.f, 0.f};
        f32x4 acc2 = {0.f, 0.f, 0.f, 0.f};
        f32x4 acc3 = {0.f, 0.f, 0.f, 0.f};
#pragma unroll
        for (int kc = 0; kc < 4; ++kc) {
            const float* ap = x + (size_t)(r0 + l16) * IN_C + kc * 32 + lg * 8;
            float4 a0 = *(const float4*)ap;
            float4 a1 = *(const float4*)(ap + 4);
            half8 af;
            af[0] = (_Float16)a0.x; af[1] = (_Float16)a0.y;
            af[2] = (_Float16)a0.z; af[3] = (_Float16)a0.w;
            af[4] = (_Float16)a1.x; af[5] = (_Float16)a1.y;
            af[6] = (_Float16)a1.z; af[7] = (_Float16)a1.w;
            acc0 = __builtin_amdgcn_mfma_f32_16x16x32_f16(af, bf[0][kc], acc0, 0, 0, 0);
            acc1 = __builtin_amdgcn_mfma_f32_16x16x32_f16(af, bf[1][kc], acc1, 0, 0, 0);
            acc2 = __builtin_amdgcn_mfma_f32_16x16x32_f16(af, bf[2][kc], acc2, 0, 0, 0);
            acc3 = __builtin_amdgcn_mfma_f32_16x16x32_f16(af, bf[3][kc], acc3, 0, 0, 0);
        }
#pragma unroll
        for (int j = 0; j < 4; ++j) {
            int   r  = r0 + lg * 4 + j;
            float dv = dinv[r];
            float v0 = acc0[j] * dv;
            float v1 = acc1[j] * dv;
            float v2 = acc2[j] * dv;
            float v3 = acc3[j] * dv;
            float m = fmaxf(fmaxf(fabsf(v0), fabsf(v1)), fmaxf(fabsf(v2), fabsf(v3)));
            m = fmaxf(m, __shfl_xor(m, 1));
            m = fmaxf(m, __shfl_xor(m, 2));
            m = fmaxf(m, __shfl_xor(m, 4));
            m = fmaxf(m, __shfl_xor(m, 8));
            float inv = (m > 0.0f) ? 127.0f / m : 0.0f;
            if (l16 == 0) scales[r] = m * (1.0f / 127.0f);
            int q0 = min(127, max(-127, __float2int_rn(v0 * inv)));
            int q1 = min(127, max(-127, __float2int_rn(v1 * inv)));
            int q2 = min(127, max(-127, __float2int_rn(v2 * inv)));
            int q3 = min(127, max(-127, __float2int_rn(v3 * inv)));
            int rl = lg * 4 + j;
            lq[rl * HID_C +  0 + l16] = (signed char)q0;
            lq[rl * HID_C + 16 + l16] = (signed char)q1;
            lq[rl * HID_C + 32 + l16] = (signed char)q2;
            lq[rl * HID_C + 48 + l16] = (signed char)q3;
        }
        uint4 wv = *(const uint4*)(lq + lane * 16);
        *(uint4*)(g1q + (size_t)r0 * HID_C + lane * 16) = wv;
    }
}

// ---------------------------------------------------------------------------
// pull layer1: 2 nodes/wave, 8 slots x 4 lanes x uint4 (R15 form).
// ---------------------------------------------------------------------------
__global__ void k_pull1(const int* __restrict__ cursor, const int* __restrict__ cnt,
                        const int* __restrict__ esrc, const float* __restrict__ dinv,
                        const uint4* __restrict__ g1v, const float* __restrict__ scales,
                        const float* __restrict__ b1, half_t* __restrict__ h1) {
    int w    = threadIdx.x >> 6;
    int lane = threadIdx.x & 63;
    int hl   = lane & 31;
    int hh   = lane >> 5;            // half 0/1 -> node
    int slot = hl >> 2;              // 0..7
    int c16  = hl & 3;               // 16-channel chunk (16B)
    int n    = blockIdx.x * 8 + w * 2 + hh;

    float dn  = dinv[n];
    int start = cursor[n];
    int mycnt = cnt[n];

    float a[16];
#pragma unroll
    for (int j = 0; j < 16; ++j) a[j] = 0.f;
    if (slot == 0)
        acc16(a, g1v[(size_t)n * 4 + c16], scales[n]);  // self row

    int maxcnt = max(mycnt, __shfl_xor(mycnt, 32));     // wave-uniform

    int e = 0;
    for (; e + 16 <= maxcnt; e += 16) {
        bool ok0 = (e + slot) < mycnt;
        bool ok1 = (e + 8 + slot) < mycnt;
        int i0 = esrc[ok0 ? (start + e + slot) : start];
        int i1 = esrc[ok1 ? (start + e + 8 + slot) : start];
        i0 = ok0 ? i0 : 0;
        i1 = ok1 ? i1 : 0;
        uint4 v0 = g1v[(size_t)i0 * 4 + c16];
        float s0 = ok0 ? scales[i0] : 0.f;
        uint4 v1 = g1v[(size_t)i1 * 4 + c16];
        float s1 = ok1 ? scales[i1] : 0.f;
        acc16(a, v0, s0);
        acc16(a, v1, s1);
    }
    for (; e < maxcnt; e += 8) {
        bool ok = (e + slot) < mycnt;
        int idx = esrc[ok ? (start + e + slot) : start];
        idx = ok ? idx : 0;
        uint4 v = g1v[(size_t)idx * 4 + c16];
        float s = ok ? scales[idx] : 0.f;
        acc16(a, v, s);
    }

#pragma unroll
    for (int j = 0; j < 16; ++j) {
        a[j] += __shfl_xor(a[j], 4);
        a[j] += __shfl_xor(a[j], 8);
        a[j] += __shfl_xor(a[j], 16);
    }

    if (slot == 0) {
        const float4* bp = (const float4*)(b1 + c16 * 16);
        uint4 u0, u1;
        unsigned us[8];
#pragma unroll
        for (int q = 0; q < 4; ++q) {
            float4 bb = bp[q];
            float r0 = fmaxf(dn * a[q * 4 + 0] + bb.x, 0.f);
            float r1 = fmaxf(dn * a[q * 4 + 1] + bb.y, 0.f);
            float r2 = fmaxf(dn * a[q * 4 + 2] + bb.z, 0.f);
            float r3 = fmaxf(dn * a[q * 4 + 3] + bb.w, 0.f);
            half2_t p0; p0.x = (_Float16)r0; p0.y = (_Float16)r1;
            half2_t p1; p1.x = (_Float16)r2; p1.y = (_Float16)r3;
            us[q * 2 + 0] = __builtin_bit_cast(unsigned, p0);
            us[q * 2 + 1] = __builtin_bit_cast(unsigned, p1);
        }
        u0.x = us[0]; u0.y = us[1]; u0.z = us[2]; u0.w = us[3];
        u1.x = us[4]; u1.y = us[5]; u1.z = us[6]; u1.w = us[7];
        half_t* hp = h1 + (size_t)n * HID_C + c16 * 16;
        *(uint4*)hp = u0;
        *(uint4*)(hp + 8) = u1;
    }
}

// ---------------------------------------------------------------------------
// MFMA GEMM2: g2 = dinv * (h1 @ W2), int8 row-quantized, 64B PADDED rows
// (40 data + 24 zero) + scales2. LDS block zero-initialized.
// ---------------------------------------------------------------------------
__global__ void k_gemm2_mfma(const half_t* __restrict__ h1, const half_t* __restrict__ W2T,
                             const float* __restrict__ dinv, signed char* __restrict__ g2q,
                             float* __restrict__ scales2) {
    __shared__ __align__(16) signed char lq[16 * 64];
    int lane = threadIdx.x & 63;
    int l16  = lane & 15;
    int lg   = lane >> 4;

    half8 bf[3][2];
#pragma unroll
    for (int ct = 0; ct < 3; ++ct)
#pragma unroll
        for (int kc = 0; kc < 2; ++kc)
            bf[ct][kc] = *(const half8*)(W2T + (ct * 16 + l16) * HID_C + kc * 32 + lg * 8);

#pragma unroll
    for (int s = 0; s < 2; ++s) {
        int r0 = (blockIdx.x * 2 + s) * 16;
        // zero the staging block (covers the 24B/row padding)
        ((uint4*)lq)[lane] = uint4{0u, 0u, 0u, 0u};
        f32x4 acc0 = {0.f, 0.f, 0.f, 0.f};
        f32x4 acc1 = {0.f, 0.f, 0.f, 0.f};
        f32x4 acc2 = {0.f, 0.f, 0.f, 0.f};
#pragma unroll
        for (int kc = 0; kc < 2; ++kc) {
            half8 af = *(const half8*)(h1 + (size_t)(r0 + l16) * HID_C + kc * 32 + lg * 8);
            acc0 = __builtin_amdgcn_mfma_f32_16x16x32_f16(af, bf[0][kc], acc0, 0, 0, 0);
            acc1 = __builtin_amdgcn_mfma_f32_16x16x32_f16(af, bf[1][kc], acc1, 0, 0, 0);
            acc2 = __builtin_amdgcn_mfma_f32_16x16x32_f16(af, bf[2][kc], acc2, 0, 0, 0);
        }
#pragma unroll
        for (int j = 0; j < 4; ++j) {
            int   r  = r0 + lg * 4 + j;
            float dv = dinv[r];
            float v0 = acc0[j] * dv;
            float v1 = acc1[j] * dv;
            float v2 = (l16 < 8) ? acc2[j] * dv : 0.0f;
            float m = fmaxf(fmaxf(fabsf(v0), fabsf(v1)), fabsf(v2));
            m = fmaxf(m, __shfl_xor(m, 1));
            m = fmaxf(m, __shfl_xor(m, 2));
            m = fmaxf(m, __shfl_xor(m, 4));
            m = fmaxf(m, __shfl_xor(m, 8));
            float inv = (m > 0.0f) ? 127.0f / m : 0.0f;
            if (l16 == 0) scales2[r] = m * (1.0f / 127.0f);
            int q0 = min(127, max(-127, __float2int_rn(v0 * inv)));
            int q1 = min(127, max(-127, __float2int_rn(v1 * inv)));
            int q2 = min(127, max(-127, __float2int_rn(v2 * inv)));
            int rl = lg * 4 + j;
            lq[rl * 64 +  0 + l16] = (signed char)q0;
            lq[rl * 64 + 16 + l16] = (signed char)q1;
            if (l16 < 8) lq[rl * 64 + 32 + l16] = (signed char)q2;
        }
        // 16 rows x 64B = 1024B = 64 lanes x 16B
        *(uint4*)(g2q + (size_t)r0 * 64 + lane * 16) = ((const uint4*)lq)[lane];
    }
}

// ---------------------------------------------------------------------------
// pull layer2 -> out: 2 nodes/wave, 8 slots x 4 lanes x uint4, 64B padded
// rows (padding = 0 so no masking). Butterfly; slot0 writes 40 fp32.
// ---------------------------------------------------------------------------
__global__ void k_pull2(const int* __restrict__ cursor, const int* __restrict__ cnt,
                        const int* __restrict__ esrc, const float* __restrict__ dinv,
                        const uint4* __restrict__ g2v, const float* __restrict__ scales2,
                        const float* __restrict__ b2, float* __restrict__ out) {
    int w    = threadIdx.x >> 6;
    int lane = threadIdx.x & 63;
    int hl   = lane & 31;
    int hh   = lane >> 5;            // half 0/1 -> node
    int slot = hl >> 2;              // 0..7
    int c16  = hl & 3;               // 16-channel chunk
    int n    = blockIdx.x * 8 + w * 2 + hh;

    float dn  = dinv[n];
    int start = cursor[n];
    int mycnt = cnt[n];

    float a[16];
#pragma unroll
    for (int j = 0; j < 16; ++j) a[j] = 0.f;
    if (slot == 0)
        acc16(a, g2v[(size_t)n * 4 + c16], scales2[n]);  // self row

    int maxcnt = max(mycnt, __shfl_xor(mycnt, 32));      // wave-uniform

    int e = 0;
    for (; e + 16 <= maxcnt; e += 16) {
        bool ok0 = (e + slot) < mycnt;
        bool ok1 = (e + 8 + slot) < mycnt;
        int i0 = esrc[ok0 ? (start + e + slot) : start];
        int i1 = esrc[ok1 ? (start + e + 8 + slot) : start];
        i0 = ok0 ? i0 : 0;
        i1 = ok1 ? i1 : 0;
        uint4 v0 = g2v[(size_t)i0 * 4 + c16];
        float s0 = ok0 ? scales2[i0] : 0.f;
        uint4 v1 = g2v[(size_t)i1 * 4 + c16];
        float s1 = ok1 ? scales2[i1] : 0.f;
        acc16(a, v0, s0);
        acc16(a, v1, s1);
    }
    for (; e < maxcnt; e += 8) {
        bool ok = (e + slot) < mycnt;
        int idx = esrc[ok ? (start + e + slot) : start];
        idx = ok ? idx : 0;
        uint4 v = g2v[(size_t)idx * 4 + c16];
        float s = ok ? scales2[idx] : 0.f;
        acc16(a, v, s);
    }

#pragma unroll
    for (int j = 0; j < 16; ++j) {
        a[j] += __shfl_xor(a[j], 4);
        a[j] += __shfl_xor(a[j], 8);
        a[j] += __shfl_xor(a[j], 16);
    }

    if (slot == 0 && c16 < 3) {
        int nvalid = (c16 < 2) ? 16 : 8;   // channels c16*16 .. +nvalid
        const float* bp = b2 + c16 * 16;
        float* op = out + (size_t)n * OUT_C + c16 * 16;
#pragma unroll
        for (int q = 0; q < 4; ++q) {
            if (q * 4 < nvalid) {
                float4 r;
                r.x = bp[q * 4 + 0] + dn * a[q * 4 + 0];
                r.y = bp[q * 4 + 1] + dn * a[q * 4 + 1];
                r.z = bp[q * 4 + 2] + dn * a[q * 4 + 2];
                r.w = bp[q * 4 + 3] + dn * a[q * 4 + 3];
                ((float4*)op)[q] = r;
            }
        }
    }
}

// ---------------------------------------------------------------------------
// launch
// ---------------------------------------------------------------------------
extern "C" void kernel_launch(void* const* d_in, const int* in_sizes, int n_in,
                              void* d_out, int out_size, void* d_ws, size_t ws_size,
                              hipStream_t stream) {
    const float* x   = (const float*)d_in[0];
    const int*   ei  = (const int*)d_in[1];
    const int*   src = ei;
    const int*   dst = ei + N_EDGES;
    const float* W1  = (const float*)d_in[2];
    const float* b1  = (const float*)d_in[3];
    const float* W2  = (const float*)d_in[4];
    const float* b2  = (const float*)d_in[5];
    float*       out = (float*)d_out;

    // workspace (~46.5 MB; proven ws >= 51.6 MB)
    const int SLAB = NBUCK * CAP;                     // 2,001,920
    int*    cnt    = (int*)d_ws;                      // N
    int*    cursor = cnt + N_NODES;                   // N
    int*    gcur   = cursor + N_NODES;                // 512 (padded)
    half_t* w1t    = (half_t*)(gcur + 512);           // 8192 halfs
    half_t* w2t    = w1t + IN_C * HID_C;              // 3072 halfs
    float*  dinv   = (float*)(w2t + 48 * HID_C);      // N
    float*  scales = dinv + N_NODES;                  // N
    float*  scales2= scales + N_NODES;                // N
    int*    srcs   = (int*)(scales2 + N_NODES);       // SLAB+8 ints (8MB)
    int*    esrc   = srcs + SLAB + 8;                 // SLAB+8 ints (8MB)
    unsigned char* d8 = (unsigned char*)(esrc + SLAB + 8);              // SLAB bytes (2MB)
    signed char* g1q = (signed char*)(((uintptr_t)(d8 + SLAB) + 127) & ~(uintptr_t)127); // N*64B
    half_t* h1 = (half_t*)(g1q + (size_t)N_NODES * 64);                 // N*64 halfs
    signed char* g2q = (signed char*)(h1 + (size_t)N_NODES * HID_C);    // N*64B (padded)

    // build (3 kernels)
    k_init<<<1, 512, 0, stream>>>(W1, W2, w1t, w2t, gcur);
    k_part<<<NPB, 256, 0, stream>>>(src, dst, gcur, srcs, d8);
    k_bbuild<<<NBUCK, 256, 0, stream>>>(srcs, d8, gcur, cursor, cnt, dinv, esrc);

    // layer 1 transform: g1q = int8(dinv * (x @ W1)), per-row scales
    k_gemm1_mfma<<<N_NODES / 32, 64, 0, stream>>>(x, w1t, dinv, g1q, scales);

    // pull layer 1 -> h1 (fp16 hidden, bias+relu applied); 2 nodes/wave
    k_pull1<<<N_NODES / 8, 256, 0, stream>>>(cursor, cnt, esrc, dinv,
                                             (const uint4*)g1q, scales, b1, h1);

    // GEMM2 (MFMA): g2q = int8(dinv * (h1 @ W2)), 64B padded rows + scales2
    k_gemm2_mfma<<<N_NODES / 32, 64, 0, stream>>>(h1, w2t, dinv, g2q, scales2);

    // pull layer 2 -> out; 2 nodes/wave
    k_pull2<<<N_NODES / 8, 256, 0, stream>>>(cursor, cnt, esrc, dinv,
                                             (const uint4*)g2q, scales2, b2, out);
}